// Round 12
// baseline (161.729 us; speedup 1.0000x reference)
//
#include <hip/hip_runtime.h>
#include <math.h>

#define DIM   64
#define HID   512
#define BATCH 8192
#define REC   1536   // floats per sorted step record: [mu 512 | alpha 512 | w1 512]

// ws layout (float/int indices into ws)
#define REC64      (64 * REC)          // 98304 floats of records
#define CNTMU_I    REC64               // int[64]: nonzeros in masked mu row i  (prefix length)
#define CNTAL_I    (REC64 + 64)        // int[64]: nonzeros in masked alpha row (prefix length)
#define CNTUP_I    (REC64 + 128)       // int[64]: start of nonzero suffix of w1 col i
#define B1S_OFF    (REC64 + 192)       // float[512]: b1 permuted
#define W2SUMS_OFF (B1S_OFF + 512)     // float[512]: logdet fold vector, permuted
#define B2SUM_OFF  (W2SUMS_OFF + 512)  // float: sum b2[64:]
#define SIGMA_I    (B2SUM_OFF + 1)     // int[512]: sort permutation
#define WS_FLOATS  (SIGMA_I + 512)

typedef float f32x4 __attribute__((ext_vector_type(4)));

// prep1: sort hidden units by MADE degree m0 (counting sort), count prefix/suffix bounds
__global__ void prep1(const float* __restrict__ mask1,
                      const float* __restrict__ mask2,
                      const float* __restrict__ b2,
                      float* __restrict__ ws) {
    __shared__ int hist[64];
    __shared__ int off[64];
    const int j = threadIdx.x;   // 512 threads, 1 block
    if (j < 64) hist[j] = 0;
    __syncthreads();
    float s = 0.f;
    for (int i = 0; i < DIM; ++i) s += mask1[j * DIM + i];
    const int m0 = (int)(s + 0.5f) - 1;   // 0..62
    atomicAdd(&hist[m0], 1);
    __syncthreads();
    if (j == 0) {
        int run = 0;
        for (int v = 0; v < 64; ++v) { off[v] = run; run += hist[v]; }
    }
    __syncthreads();
    const int pos = atomicAdd(&off[m0], 1);
    ((int*)ws)[SIGMA_I + pos] = j;
    if (j < 64) {
        float sm = 0.f, sa = 0.f, su = 0.f;
        for (int k = 0; k < HID; ++k) sm += mask2[j * HID + k];
        for (int k = 0; k < HID; ++k) sa += mask2[(DIM + j) * HID + k];
        for (int r = 0; r < HID; ++r) su += mask1[r * DIM + j];
        int* ci = (int*)ws;
        ci[CNTMU_I + j] = (int)(sm + 0.5f);
        ci[CNTAL_I + j] = (int)(sa + 0.5f);
        ci[CNTUP_I + j] = HID - (int)(su + 0.5f);
    }
    if (j == 0) {
        float s2 = 0.f;
        for (int r = 0; r < DIM; ++r) s2 += b2[DIM + r];
        ws[B2SUM_OFF] = s2;
    }
}

// prep2: build permuted masked weight records + permuted b1 / logdet vector
__global__ void prep2(const float* __restrict__ W1,
                      const float* __restrict__ mask1,
                      const float* __restrict__ W2,
                      const float* __restrict__ mask2,
                      const float* __restrict__ b1,
                      float* __restrict__ ws) {
    const int tix = blockIdx.x * blockDim.x + threadIdx.x;
    const int* sig = (const int*)ws + SIGMA_I;
    if (tix < REC64) {
        const int rec = tix / REC;
        const int pos = tix - rec * REC;
        const int sec = pos >> 9;
        const int p   = pos & 511;
        const int sj  = sig[p];
        float v;
        if (sec == 0)      v = mask2[rec * HID + sj] * W2[rec * HID + sj];
        else if (sec == 1) v = mask2[(DIM + rec) * HID + sj] * W2[(DIM + rec) * HID + sj];
        else               v = mask1[sj * DIM + rec] * W1[sj * DIM + rec];
        ws[tix] = v;
    } else if (tix < REC64 + 512) {
        const int p = tix - REC64;
        ws[B1S_OFF + p] = b1[sig[p]];
    } else if (tix < REC64 + 1024) {
        const int p  = tix - REC64 - 512;
        const int sj = sig[p];
        float acc = 0.f;
        for (int r = 0; r < DIM; ++r)
            acc += mask2[(DIM + r) * HID + sj] * W2[(DIM + r) * HID + sj];
        ws[W2SUMS_OFF + p] = acc;
    }
}

// 4-stage butterfly sum within each 16-lane group; result broadcast to all 16 lanes.
__device__ __forceinline__ float grp_red16(float x) {
    x += __int_as_float(__builtin_amdgcn_update_dpp(0, __float_as_int(x), 0xB1,  0xf, 0xf, true)); // quad_perm [1,0,3,2] : xor1
    x += __int_as_float(__builtin_amdgcn_update_dpp(0, __float_as_int(x), 0x4E,  0xf, 0xf, true)); // quad_perm [2,3,0,1] : xor2
    x += __int_as_float(__builtin_amdgcn_update_dpp(0, __float_as_int(x), 0x141, 0xf, 0xf, true)); // row_half_mirror: cross-quad in 8
    x += __int_as_float(__builtin_amdgcn_update_dpp(0, __float_as_int(x), 0x140, 0xf, 0xf, true)); // row_mirror: cross-8 in 16
    return x;
}

// one wave = 4 batch rows, one row per 16-lane group; lane holds h[8] f32x4 (k = b*64 + t*4 + e)
__global__ __launch_bounds__(256, 2) void maf_kernel(
    const float* __restrict__ z,
    const float* __restrict__ b2,
    const float* __restrict__ ws,
    float* __restrict__ out) {
    const int lane = threadIdx.x & 63;
    const int t    = lane & 15;
    const int wid  = (blockIdx.x * blockDim.x + threadIdx.x) >> 6;
    const int row  = wid * 4 + (lane >> 4);
    const f32x4 Z4 = {0.f, 0.f, 0.f, 0.f};

    f32x4 h[8];
#pragma unroll
    for (int b = 0; b < 8; ++b)
        h[b] = *(const f32x4*)(ws + B1S_OFF + b * 64 + t * 4);

    const int* ci = (const int*)ws;
    const int cmu_l = ci[CNTMU_I + lane];
    const int cal_l = ci[CNTAL_I + lane];
    const int cup_l = ci[CNTUP_I + lane];
    const float b2lo = b2[lane];
    const float b2hi = b2[DIM + lane];

    // wp -> record + 768 floats (+ lane slice): mu at wp-768, alpha at wp-256, w1 at wp+256
    const float* wp = ws + 768 + t * 4;

#pragma unroll 1
    for (int i = 0; i < DIM; ++i) {
        const int cm = __builtin_amdgcn_readlane(cmu_l, i);
        const int ca = __builtin_amdgcn_readlane(cal_l, i);
        const int cu = __builtin_amdgcn_readlane(cup_l, i);
        const float zi = z[row * DIM + i];   // same addr within group -> broadcast

        f32x4 A[8], M[8], U[8];
#pragma unroll
        for (int b = 0; b < 8; ++b) {
            M[b] = *(const f32x4*)(wp - 768 + b * 64);
            A[b] = *(const f32x4*)(wp - 256 + b * 64);
            U[b] = *(const f32x4*)(wp + 256 + b * 64);
        }
        __builtin_amdgcn_s_barrier();   // keep block's waves aligned for L1 reuse

        f32x4 amv = Z4, aav = Z4;
#pragma unroll
        for (int b = 0; b < 8; ++b) {
            if (ca > 64 * b) {                       // uniform: alpha prefix covers this block
                f32x4 q = __builtin_elementwise_max(h[b], Z4);
                aav += q * A[b];
                if (cm > 64 * b) amv += q * M[b];    // mu prefix is shorter
            }
        }
        float pa = (aav.x + aav.y) + (aav.z + aav.w);
        float pm = (amv.x + amv.y) + (amv.z + amv.w);
        pa = grp_red16(pa);
        pm = grp_red16(pm);

        const float mu = pm + __int_as_float(__builtin_amdgcn_readlane(__float_as_int(b2lo), i));
        const float al = pa + __int_as_float(__builtin_amdgcn_readlane(__float_as_int(b2hi), i));
        const float xv = zi * __expf(al) + mu;       // group-uniform

        if (t == 0) out[row * DIM + i] = xv;

#pragma unroll
        for (int b = 0; b < 8; ++b) {
            if (64 * b + 64 > cu) {                  // uniform: w1 suffix intersects block
                f32x4 xs4 = {xv, xv, xv, xv};
                h[b] += U[b] * xs4;
            }
        }
        wp += REC;
    }

    // log-det: relu(h_final) . w2sums + sum(b2[64:])
    f32x4 acc = Z4;
#pragma unroll
    for (int b = 0; b < 8; ++b) {
        f32x4 S = *(const f32x4*)(ws + W2SUMS_OFF + b * 64 + t * 4);
        acc += __builtin_elementwise_max(h[b], Z4) * S;
    }
    float pl = (acc.x + acc.y) + (acc.z + acc.w);
    pl = grp_red16(pl);
    if (t == 0) out[BATCH * DIM + row] = pl + ws[B2SUM_OFF];
}

extern "C" void kernel_launch(void* const* d_in, const int* in_sizes, int n_in,
                              void* d_out, int out_size, void* d_ws, size_t ws_size,
                              hipStream_t stream) {
    const float* z     = (const float*)d_in[0];
    const float* W1    = (const float*)d_in[1];
    const float* b1    = (const float*)d_in[2];
    const float* W2    = (const float*)d_in[3];
    const float* b2    = (const float*)d_in[4];
    const float* mask1 = (const float*)d_in[5];
    const float* mask2 = (const float*)d_in[6];
    float* out = (float*)d_out;
    float* ws  = (float*)d_ws;

    prep1<<<1, 512, 0, stream>>>(mask1, mask2, b2, ws);
    {
        int total  = REC64 + 1024;
        int blocks = (total + 255) / 256;
        prep2<<<blocks, 256, 0, stream>>>(W1, mask1, W2, mask2, b1, ws);
    }
    {
        int threads = 256;                 // 4 waves/block, 4 rows per wave
        int blocks  = BATCH / 16;          // 512 blocks = 2048 waves
        maf_kernel<<<blocks, threads, 0, stream>>>(z, b2, ws, out);
    }
}

// Round 14
// 130.565 us; speedup vs baseline: 1.2387x; 1.2387x over previous
//
#include <hip/hip_runtime.h>
#include <math.h>

#define DIM   64
#define HID   512
#define BATCH 8192
#define REC   1536   // floats per sorted step record: [mu 512 | alpha 512 | w1 512]

// ws layout (float/int indices into ws)
#define REC64      (64 * REC)          // 98304 floats of records
#define CNTMU_I    REC64               // int[64]: nonzeros in masked mu row i  (prefix length)
#define CNTAL_I    (REC64 + 64)        // int[64]: nonzeros in masked alpha row (prefix length)
#define CNTUP_I    (REC64 + 128)       // int[64]: start of nonzero suffix of w1 col i
#define B1S_OFF    (REC64 + 192)       // float[512]: b1 permuted
#define W2SUMS_OFF (B1S_OFF + 512)     // float[512]: logdet fold vector, permuted
#define B2SUM_OFF  (W2SUMS_OFF + 512)  // float: sum b2[64:]
#define SIGMA_I    (B2SUM_OFF + 1)     // int[512]: sort permutation
#define WS_FLOATS  (SIGMA_I + 512)

typedef float f32x4 __attribute__((ext_vector_type(4)));

// prep1: sort hidden units by MADE degree m0 (counting sort), count prefix/suffix bounds
__global__ void prep1(const float* __restrict__ mask1,
                      const float* __restrict__ mask2,
                      const float* __restrict__ b2,
                      float* __restrict__ ws) {
    __shared__ int hist[64];
    __shared__ int off[64];
    const int j = threadIdx.x;   // 512 threads, 1 block
    if (j < 64) hist[j] = 0;
    __syncthreads();
    float s = 0.f;
    for (int i = 0; i < DIM; ++i) s += mask1[j * DIM + i];
    const int m0 = (int)(s + 0.5f) - 1;   // 0..62
    atomicAdd(&hist[m0], 1);
    __syncthreads();
    if (j == 0) {
        int run = 0;
        for (int v = 0; v < 64; ++v) { off[v] = run; run += hist[v]; }
    }
    __syncthreads();
    const int pos = atomicAdd(&off[m0], 1);
    ((int*)ws)[SIGMA_I + pos] = j;
    if (j < 64) {
        float sm = 0.f, sa = 0.f, su = 0.f;
        for (int k = 0; k < HID; ++k) sm += mask2[j * HID + k];
        for (int k = 0; k < HID; ++k) sa += mask2[(DIM + j) * HID + k];
        for (int r = 0; r < HID; ++r) su += mask1[r * DIM + j];
        int* ci = (int*)ws;
        ci[CNTMU_I + j] = (int)(sm + 0.5f);
        ci[CNTAL_I + j] = (int)(sa + 0.5f);
        ci[CNTUP_I + j] = HID - (int)(su + 0.5f);
    }
    if (j == 0) {
        float s2 = 0.f;
        for (int r = 0; r < DIM; ++r) s2 += b2[DIM + r];
        ws[B2SUM_OFF] = s2;
    }
}

// prep2: build permuted masked weight records + permuted b1 / logdet vector
__global__ void prep2(const float* __restrict__ W1,
                      const float* __restrict__ mask1,
                      const float* __restrict__ W2,
                      const float* __restrict__ mask2,
                      const float* __restrict__ b1,
                      float* __restrict__ ws) {
    const int tix = blockIdx.x * blockDim.x + threadIdx.x;
    const int* sig = (const int*)ws + SIGMA_I;
    if (tix < REC64) {
        const int rec = tix / REC;
        const int pos = tix - rec * REC;
        const int sec = pos >> 9;
        const int p   = pos & 511;
        const int sj  = sig[p];
        float v;
        if (sec == 0)      v = mask2[rec * HID + sj] * W2[rec * HID + sj];
        else if (sec == 1) v = mask2[(DIM + rec) * HID + sj] * W2[(DIM + rec) * HID + sj];
        else               v = mask1[sj * DIM + rec] * W1[sj * DIM + rec];
        ws[tix] = v;
    } else if (tix < REC64 + 512) {
        const int p = tix - REC64;
        ws[B1S_OFF + p] = b1[sig[p]];
    } else if (tix < REC64 + 1024) {
        const int p  = tix - REC64 - 512;
        const int sj = sig[p];
        float acc = 0.f;
        for (int r = 0; r < DIM; ++r)
            acc += mask2[(DIM + r) * HID + sj] * W2[(DIM + r) * HID + sj];
        ws[W2SUMS_OFF + p] = acc;
    }
}

// 4-stage butterfly sum within each 16-lane group; result broadcast to all 16 lanes.
__device__ __forceinline__ float grp_red16(float x) {
    x += __int_as_float(__builtin_amdgcn_update_dpp(0, __float_as_int(x), 0xB1,  0xf, 0xf, true)); // quad_perm xor1
    x += __int_as_float(__builtin_amdgcn_update_dpp(0, __float_as_int(x), 0x4E,  0xf, 0xf, true)); // quad_perm xor2
    x += __int_as_float(__builtin_amdgcn_update_dpp(0, __float_as_int(x), 0x141, 0xf, 0xf, true)); // row_half_mirror
    x += __int_as_float(__builtin_amdgcn_update_dpp(0, __float_as_int(x), 0x140, 0xf, 0xf, true)); // row_mirror
    return x;
}

__device__ __forceinline__ float readlane_f(float v, int lane) {
    return __int_as_float(__builtin_amdgcn_readlane(__float_as_int(v), lane));
}

// one wave = 4 batch rows, one row per 16-lane group; lane holds h[8] f32x4 (k = b*64 + t*4 + e)
__global__ __launch_bounds__(256, 2) void maf_kernel(
    const float* __restrict__ z,
    const float* __restrict__ b2,
    const float* __restrict__ ws,
    float* __restrict__ out) {
    const int lane = threadIdx.x & 63;
    const int t    = lane & 15;
    const int wid  = (blockIdx.x * blockDim.x + threadIdx.x) >> 6;
    const int row  = wid * 4 + (lane >> 4);
    const f32x4 Z4 = {0.f, 0.f, 0.f, 0.f};

    f32x4 h[8];
#pragma unroll
    for (int b = 0; b < 8; ++b)
        h[b] = *(const f32x4*)(ws + B1S_OFF + b * 64 + t * 4);

    const int* ci = (const int*)ws;
    const int cmu_l = ci[CNTMU_I + lane];
    const int cal_l = ci[CNTAL_I + lane];
    const int cup_l = ci[CNTUP_I + lane];
    const float b2lo = b2[lane];
    const float b2hi = b2[DIM + lane];

// prefetch alpha slice of record at WNXT (guarded by its prefix count)
#define PF_A(AREG, WNXT, CAQ)                                                 \
    do {                                                                      \
        _Pragma("unroll")                                                     \
        for (int b = 0; b < 8; ++b)                                           \
            if ((CAQ) > 64 * b) AREG[b] = *(const f32x4*)((WNXT) + b * 64);   \
    } while (0)

// one autoregressive step; AREG holds this step's alpha weights (prefetched)
#define STEP(I, AREG, WCUR)                                                   \
    do {                                                                      \
        const int _cm = __builtin_amdgcn_readlane(cmu_l, (I));                \
        const int _ca = __builtin_amdgcn_readlane(cal_l, (I));                \
        const int _cu = __builtin_amdgcn_readlane(cup_l, (I));                \
        const float _zi = z[row * DIM + (I)];                                 \
        f32x4 _M[8], _U[8];                                                   \
        _Pragma("unroll")                                                     \
        for (int b = 0; b < 8; ++b)                                           \
            if (_cm > 64 * b) _M[b] = *(const f32x4*)((WCUR) - 512 + b * 64); \
        f32x4 _aav = Z4, _amv = Z4;                                           \
        _Pragma("unroll")                                                     \
        for (int b = 0; b < 8; ++b)                                           \
            if (_ca > 64 * b) {                                               \
                f32x4 _q = __builtin_elementwise_max(h[b], Z4);               \
                _aav += _q * AREG[b];                                         \
                if (_cm > 64 * b) _amv += _q * _M[b];                         \
            }                                                                 \
        _Pragma("unroll")                                                     \
        for (int b = 0; b < 8; ++b)                                           \
            if (64 * b + 64 > _cu)                                            \
                _U[b] = *(const f32x4*)((WCUR) + 512 + b * 64);               \
        float _pa = (_aav.x + _aav.y) + (_aav.z + _aav.w);                    \
        float _pm = (_amv.x + _amv.y) + (_amv.z + _amv.w);                    \
        _pa = grp_red16(_pa);                                                 \
        _pm = grp_red16(_pm);                                                 \
        const float _mu = _pm + readlane_f(b2lo, (I));                        \
        const float _al = _pa + readlane_f(b2hi, (I));                        \
        const float _xv = _zi * __expf(_al) + _mu;                            \
        if (t == 0) out[row * DIM + (I)] = _xv;                               \
        const f32x4 _x4 = {_xv, _xv, _xv, _xv};                               \
        _Pragma("unroll")                                                     \
        for (int b = 0; b < 8; ++b)                                           \
            if (64 * b + 64 > _cu) h[b] += _U[b] * _x4;                       \
    } while (0)

    // wp -> ALPHA section start of current record (+ lane slice); mu at -512, w1 at +512
    const float* wp = ws + 512 + t * 4;

    f32x4 AA[8], AB[8];
    {
        const int ca0 = __builtin_amdgcn_readlane(cal_l, 0);
        PF_A(AA, wp, ca0);
    }

#pragma unroll 1
    for (int i = 0; i < 64; i += 2) {
        __builtin_amdgcn_s_barrier();   // keep block's 4 waves aligned for L1 reuse
        {
            const int can1 = __builtin_amdgcn_readlane(cal_l, (i + 1) & 63);
            PF_A(AB, wp + REC, can1);
        }
        STEP(i, AA, wp);
        if (i < 62) {
            const int can2 = __builtin_amdgcn_readlane(cal_l, (i + 2) & 63);
            PF_A(AA, wp + 2 * REC, can2);
        }
        STEP(i + 1, AB, wp + REC);
        wp += 2 * REC;
    }

    // log-det: relu(h_final) . w2sums + sum(b2[64:])
    f32x4 acc = Z4;
#pragma unroll
    for (int b = 0; b < 8; ++b) {
        f32x4 S = *(const f32x4*)(ws + W2SUMS_OFF + b * 64 + t * 4);
        acc += __builtin_elementwise_max(h[b], Z4) * S;
    }
    float pl = (acc.x + acc.y) + (acc.z + acc.w);
    pl = grp_red16(pl);
    if (t == 0) out[BATCH * DIM + row] = pl + ws[B2SUM_OFF];
#undef PF_A
#undef STEP
}

extern "C" void kernel_launch(void* const* d_in, const int* in_sizes, int n_in,
                              void* d_out, int out_size, void* d_ws, size_t ws_size,
                              hipStream_t stream) {
    const float* z     = (const float*)d_in[0];
    const float* W1    = (const float*)d_in[1];
    const float* b1    = (const float*)d_in[2];
    const float* W2    = (const float*)d_in[3];
    const float* b2    = (const float*)d_in[4];
    const float* mask1 = (const float*)d_in[5];
    const float* mask2 = (const float*)d_in[6];
    float* out = (float*)d_out;
    float* ws  = (float*)d_ws;

    prep1<<<1, 512, 0, stream>>>(mask1, mask2, b2, ws);
    {
        int total  = REC64 + 1024;
        int blocks = (total + 255) / 256;
        prep2<<<blocks, 256, 0, stream>>>(W1, mask1, W2, mask2, b1, ws);
    }
    {
        int threads = 256;                 // 4 waves/block, 4 rows per wave
        int blocks  = BATCH / 16;          // 512 blocks = 2048 waves
        maf_kernel<<<blocks, threads, 0, stream>>>(z, b2, ws, out);
    }
}